// Round 12
// baseline (7700.287 us; speedup 1.0000x reference)
//
#include <hip/hip_runtime.h>
#include <hip/hip_fp16.h>
#include <math.h>

#define T_ 8
#define N_ 20000
#define E_ 320000
#define ETOT_ (E_ + N_)
#define FIN_ 32
#define C1_ 256   // HEADS*HID
#define HID_ 64
#define G3_ 384   // 3*GH
#define GH_ 128
#define MB_ 128   // edges per block
#define MT_ 8     // M-tiles per wave = MB_/16
#define LDP_ 136  // padded inner dim for LDS exchange array
#define SEG_ 4
#define ESEG_ (E_ / SEG_)          // 80000 edges per segment
#define NPACK_ (24 * 4 * 64 * 8)   // packed weight elems per matrix

typedef __attribute__((ext_vector_type(8))) _Float16 h8v;
typedef __attribute__((ext_vector_type(4))) float f4v;

// ---------------- helpers ----------------
__device__ __forceinline__ float wave_sum(float v) {
#pragma unroll
  for (int off = 32; off; off >>= 1) v += __shfl_down(v, off);
  return v;
}
__device__ __forceinline__ float sigmoidf_(float x) { return 1.f / (1.f + __expf(-x)); }
__device__ __forceinline__ float tanhf_(float x) {
  float e2 = __expf(2.f * x);
  return 1.f - 2.f / (e2 + 1.f);
}
__device__ __forceinline__ unsigned short f2h(float f) {
  return __half_as_ushort(__float2half_rn(f));
}
__device__ __forceinline__ float h2f(unsigned short u) {
  return __half2float(__ushort_as_half(u));
}
__device__ __forceinline__ void edge_sd(const int* ei, int e, int& s, int& d) {
  if (e < E_) { s = ei[e]; d = ei[E_ + e]; }
  else { s = e - E_; d = e - E_; }
}

// ---------------- CSR build (by dst) ----------------
__global__ void k_hist(const int* __restrict__ ei, int* __restrict__ counts) {
  int e = blockIdx.x * 256 + threadIdx.x;
  if (e >= ETOT_) return;
  int s, d; edge_sd(ei, e, s, d);
  atomicAdd(&counts[d], 1);
}

__global__ void k_scan(const int* __restrict__ counts, int* __restrict__ indptr) {
  __shared__ int tmp[1024];
  __shared__ int carry;
  int tid = threadIdx.x;
  if (tid == 0) { carry = 0; indptr[0] = 0; }
  __syncthreads();
  for (int base = 0; base < N_; base += 1024) {
    int i = base + tid;
    int v = (i < N_) ? counts[i] : 0;
    tmp[tid] = v;
    __syncthreads();
    for (int off = 1; off < 1024; off <<= 1) {
      int add = (tid >= off) ? tmp[tid - off] : 0;
      __syncthreads();
      tmp[tid] += add;
      __syncthreads();
    }
    if (i < N_) indptr[i + 1] = carry + tmp[tid];
    __syncthreads();
    if (tid == 1023) carry += tmp[1023];
    __syncthreads();
  }
}

__global__ void k_copy(const int* __restrict__ indptr, int* __restrict__ cursors) {
  int i = blockIdx.x * 256 + threadIdx.x;
  if (i < N_) cursors[i] = indptr[i];
}

__global__ void k_scatter(const int* __restrict__ ei, int* __restrict__ cursors,
                          int* __restrict__ csr_src) {
  int e = blockIdx.x * 256 + threadIdx.x;
  if (e >= ETOT_) return;
  int s, d; edge_sd(ei, e, s, d);
  int pos = atomicAdd(&cursors[d], 1);
  csr_src[pos] = s;
}

// ---------------- weight pack: W[384][128] fp32 -> B-fragment-ordered fp16 hi/lo ----
__global__ void k_packW16(const float* __restrict__ W, unsigned short* __restrict__ Bh,
                          unsigned short* __restrict__ Bl) {
  int idx = blockIdx.x * 256 + threadIdx.x;
  if (idx >= NPACK_) return;
  int j = idx & 7, lane = (idx >> 3) & 63, ks = (idx >> 9) & 3, nt = idx >> 11;
  int n = nt * 16 + (lane & 15);
  int k = ks * 32 + (lane >> 4) * 8 + j;
  float v = W[n * GH_ + k];
  unsigned short h = f2h(v);
  Bh[idx] = h;
  Bl[idx] = f2h(v - h2f(h));
}

// ---------------- GAT layer 1 ----------------
__global__ __launch_bounds__(256) void k_gat1_lin(
    const float* __restrict__ x, const float* __restrict__ W1,
    const float* __restrict__ as1, const float* __restrict__ ad1,
    float* __restrict__ hlin, float* __restrict__ als, float* __restrict__ ald) {
  int n = blockIdx.x;
  int j = threadIdx.x;
  __shared__ float sx[FIN_];
  if (j < FIN_) sx[j] = x[n * FIN_ + j];
  __syncthreads();
  float acc = 0.f;
#pragma unroll
  for (int k = 0; k < FIN_; ++k) acc = fmaf(sx[k], W1[k * C1_ + j], acc);
  hlin[(size_t)n * C1_ + j] = acc;
  int h = j >> 6, c = j & 63;
  float vs = wave_sum(acc * as1[h * 64 + c]);
  float vd = wave_sum(acc * ad1[h * 64 + c]);
  if (c == 0) { als[n * 4 + h] = vs; ald[n * 4 + h] = vd; }
}

__global__ __launch_bounds__(256) void k_gat1_attn(
    const int* __restrict__ csr_src, const int* __restrict__ indptr,
    const float* __restrict__ als, const float* __restrict__ ald,
    float* __restrict__ ex, float* __restrict__ sums) {
  int w = threadIdx.x >> 6, lane = threadIdx.x & 63;
  int n = blockIdx.x * 4 + w;
  int s0 = indptr[n], s1 = indptr[n + 1];
  float adv[4], mx[4], sm[4];
#pragma unroll
  for (int h = 0; h < 4; ++h) { adv[h] = ald[n * 4 + h]; mx[h] = -1e30f; sm[h] = 0.f; }
  for (int e = s0 + lane; e < s1; e += 64) {
    int s = csr_src[e];
#pragma unroll
    for (int h = 0; h < 4; ++h) {
      float sc = als[s * 4 + h] + adv[h];
      sc = sc >= 0.f ? sc : 0.2f * sc;
      ex[(size_t)e * 4 + h] = sc;
      mx[h] = fmaxf(mx[h], sc);
    }
  }
#pragma unroll
  for (int h = 0; h < 4; ++h) {
#pragma unroll
    for (int off = 32; off; off >>= 1) mx[h] = fmaxf(mx[h], __shfl_xor(mx[h], off));
  }
  for (int e = s0 + lane; e < s1; e += 64) {
#pragma unroll
    for (int h = 0; h < 4; ++h) {
      float v = __expf(ex[(size_t)e * 4 + h] - mx[h]);
      ex[(size_t)e * 4 + h] = v;
      sm[h] += v;
    }
  }
#pragma unroll
  for (int h = 0; h < 4; ++h) sm[h] = wave_sum(sm[h]);
  if (lane == 0) {
#pragma unroll
    for (int h = 0; h < 4; ++h) sums[n * 4 + h] = sm[h];
  }
}

__global__ __launch_bounds__(256) void k_gat1_agg(
    const int* __restrict__ csr_src, const int* __restrict__ indptr,
    const float* __restrict__ ex, const float* __restrict__ sums,
    const float* __restrict__ hlin, const float* __restrict__ b1,
    float* __restrict__ h1out) {
  int n = blockIdx.x;
  int j = threadIdx.x;
  int hh = j >> 6;
  int s0 = indptr[n], s1 = indptr[n + 1];
  float inv = 1.f / (sums[n * 4 + hh] + 1e-16f);
  float acc = 0.f;
  for (int e = s0; e < s1; ++e) {
    int s = csr_src[e];
    float a = ex[(size_t)e * 4 + hh] * inv;
    acc = fmaf(a, hlin[(size_t)s * C1_ + j], acc);
  }
  float o = acc + b1[j];
  h1out[(size_t)n * C1_ + j] = o > 0.f ? o : expm1f(o);
}

// ---------------- GAT layer 2 ----------------
__global__ __launch_bounds__(256) void k_gat2_lin(
    const float* __restrict__ h1out, const float* __restrict__ W2,
    const float* __restrict__ as2, const float* __restrict__ ad2,
    float* __restrict__ hlin2, float* __restrict__ als, float* __restrict__ ald) {
  int w = threadIdx.x >> 6, lane = threadIdx.x & 63;
  int n = blockIdx.x * 4 + w;
  __shared__ float sx[4][C1_];
  for (int k = lane; k < C1_; k += 64) sx[w][k] = h1out[(size_t)n * C1_ + k];
  __syncthreads();
  float acc = 0.f;
#pragma unroll 4
  for (int k = 0; k < C1_; ++k) acc = fmaf(sx[w][k], W2[k * HID_ + lane], acc);
  hlin2[(size_t)n * HID_ + lane] = acc;
  float vs = wave_sum(acc * as2[lane]);
  float vd = wave_sum(acc * ad2[lane]);
  if (lane == 0) { als[n] = vs; ald[n] = vd; }
}

__global__ __launch_bounds__(256) void k_gat2_attn(
    const int* __restrict__ csr_src, const int* __restrict__ indptr,
    const float* __restrict__ als, const float* __restrict__ ald,
    float* __restrict__ ex, float* __restrict__ sums) {
  int w = threadIdx.x >> 6, lane = threadIdx.x & 63;
  int n = blockIdx.x * 4 + w;
  int s0 = indptr[n], s1 = indptr[n + 1];
  float adv = ald[n];
  float mx = -1e30f, sm = 0.f;
  for (int e = s0 + lane; e < s1; e += 64) {
    float sc = als[csr_src[e]] + adv;
    sc = sc >= 0.f ? sc : 0.2f * sc;
    ex[e] = sc;
    mx = fmaxf(mx, sc);
  }
#pragma unroll
  for (int off = 32; off; off >>= 1) mx = fmaxf(mx, __shfl_xor(mx, off));
  for (int e = s0 + lane; e < s1; e += 64) {
    float v = __expf(ex[e] - mx);
    ex[e] = v;
    sm += v;
  }
  sm = wave_sum(sm);
  if (lane == 0) sums[n] = sm;
}

// writes h2 as fp16 (A-operand of the layer-0 input MFMA)
__global__ __launch_bounds__(256) void k_gat2_agg(
    const int* __restrict__ csr_src, const int* __restrict__ indptr,
    const float* __restrict__ ex, const float* __restrict__ sums,
    const float* __restrict__ hlin2, const float* __restrict__ b2,
    unsigned short* __restrict__ h2f16) {
  int w = threadIdx.x >> 6, lane = threadIdx.x & 63;
  int n = blockIdx.x * 4 + w;
  int s0 = indptr[n], s1 = indptr[n + 1];
  float inv = 1.f / (sums[n] + 1e-16f);
  float acc = 0.f;
  for (int e = s0; e < s1; ++e) {
    int s = csr_src[e];
    acc = fmaf(ex[e] * inv, hlin2[(size_t)s * HID_ + lane], acc);
  }
  h2f16[(size_t)n * HID_ + lane] = f2h(acc + b2[lane]);
}

// ---------------- MFMA GRU step (t-outer, fp16 global states, no staging) ----
// fp16x2: C += A*(Bh+Bl); A single fp16, W split fp16 hi/lo
__device__ __forceinline__ void mfma2h(f4v& acc, h8v a, h8v bh, h8v bl) {
  acc = __builtin_amdgcn_mfma_f32_16x16x32_f16(a, bh, acc, 0, 0, 0);
  acc = __builtin_amdgcn_mfma_f32_16x16x32_f16(a, bl, acc, 0, 0, 0);
}

// LDS pass (gi1): A = new-h0 fp16 in LDS (LDP_ stride)
__device__ __forceinline__ void mfma_pass(
    const unsigned short* A_,
    const unsigned short* __restrict__ Bh_, const unsigned short* __restrict__ Bl_,
    int w, int lane, f4v Cr[MT_], f4v Cz[MT_], f4v Cn[MT_]) {
  const int mrow = lane & 15, quad = lane >> 4;
#pragma unroll
  for (int ks = 0; ks < 4; ++ks) {
    h8v A[MT_];
    const int aoff = mrow * LDP_ + ks * 32 + quad * 8;
#pragma unroll
    for (int mt = 0; mt < MT_; ++mt) A[mt] = *(const h8v*)(A_ + aoff + mt * (16 * LDP_));
    {
      const int nt = w;
      const h8v bh = *(const h8v*)(Bh_ + ((size_t)(nt * 4 + ks) * 64 + lane) * 8);
      const h8v bl = *(const h8v*)(Bl_ + ((size_t)(nt * 4 + ks) * 64 + lane) * 8);
#pragma unroll
      for (int mt = 0; mt < MT_; ++mt) mfma2h(Cr[mt], A[mt], bh, bl);
    }
    {
      const int nt = 8 + w;
      const h8v bh = *(const h8v*)(Bh_ + ((size_t)(nt * 4 + ks) * 64 + lane) * 8);
      const h8v bl = *(const h8v*)(Bl_ + ((size_t)(nt * 4 + ks) * 64 + lane) * 8);
#pragma unroll
      for (int mt = 0; mt < MT_; ++mt) mfma2h(Cz[mt], A[mt], bh, bl);
    }
    {
      const int nt = 16 + w;
      const h8v bh = *(const h8v*)(Bh_ + ((size_t)(nt * 4 + ks) * 64 + lane) * 8);
      const h8v bl = *(const h8v*)(Bl_ + ((size_t)(nt * 4 + ks) * 64 + lane) * 8);
#pragma unroll
      for (int mt = 0; mt < MT_; ++mt) mfma2h(Cn[mt], A[mt], bh, bl);
    }
  }
}

// global state pass (gh0/gh1): A = fp16 state rows [128 edges][GH_], contiguous
__device__ __forceinline__ void mfma_pass_g(
    const unsigned short* __restrict__ S,   // state base + le0*GH_
    const unsigned short* __restrict__ Bh_, const unsigned short* __restrict__ Bl_,
    int w, int lane, f4v Cr[MT_], f4v Cz[MT_], f4v Cn[MT_]) {
  const int mrow = lane & 15, quad = lane >> 4;
#pragma unroll
  for (int ks = 0; ks < 4; ++ks) {
    h8v A[MT_];
    const int off = ks * 32 + quad * 8;
#pragma unroll
    for (int mt = 0; mt < MT_; ++mt)
      A[mt] = *(const h8v*)(S + (size_t)(mt * 16 + mrow) * GH_ + off);
    {
      const int nt = w;
      const h8v bh = *(const h8v*)(Bh_ + ((size_t)(nt * 4 + ks) * 64 + lane) * 8);
      const h8v bl = *(const h8v*)(Bl_ + ((size_t)(nt * 4 + ks) * 64 + lane) * 8);
#pragma unroll
      for (int mt = 0; mt < MT_; ++mt) mfma2h(Cr[mt], A[mt], bh, bl);
    }
    {
      const int nt = 8 + w;
      const h8v bh = *(const h8v*)(Bh_ + ((size_t)(nt * 4 + ks) * 64 + lane) * 8);
      const h8v bl = *(const h8v*)(Bl_ + ((size_t)(nt * 4 + ks) * 64 + lane) * 8);
#pragma unroll
      for (int mt = 0; mt < MT_; ++mt) mfma2h(Cz[mt], A[mt], bh, bl);
    }
    {
      const int nt = 16 + w;
      const h8v bh = *(const h8v*)(Bh_ + ((size_t)(nt * 4 + ks) * 64 + lane) * 8);
      const h8v bl = *(const h8v*)(Bl_ + ((size_t)(nt * 4 + ks) * 64 + lane) * 8);
#pragma unroll
      for (int mt = 0; mt < MT_; ++mt) mfma2h(Cn[mt], A[mt], bh, bl);
    }
  }
}

// X pass (gi0): A from h2 slice, node-gathered (L2-hot single-t slice)
__device__ __forceinline__ void mfma_pass_x(
    const unsigned short* __restrict__ h2,
    const int esrc[MT_], const int edst[MT_],
    const unsigned short* __restrict__ Bh_, const unsigned short* __restrict__ Bl_,
    int w, int lane, f4v Cr[MT_], f4v Cz[MT_], f4v Cn[MT_]) {
  const int quad = lane >> 4;
#pragma unroll
  for (int ks = 0; ks < 4; ++ks) {
    h8v A[MT_];
    const int choff = (ks & 1) * 32 + quad * 8;
#pragma unroll
    for (int mt = 0; mt < MT_; ++mt) {
      const int node = (ks < 2) ? esrc[mt] : edst[mt];
      A[mt] = *(const h8v*)(h2 + (size_t)node * HID_ + choff);
    }
    {
      const int nt = w;
      const h8v bh = *(const h8v*)(Bh_ + ((size_t)(nt * 4 + ks) * 64 + lane) * 8);
      const h8v bl = *(const h8v*)(Bl_ + ((size_t)(nt * 4 + ks) * 64 + lane) * 8);
#pragma unroll
      for (int mt = 0; mt < MT_; ++mt) mfma2h(Cr[mt], A[mt], bh, bl);
    }
    {
      const int nt = 8 + w;
      const h8v bh = *(const h8v*)(Bh_ + ((size_t)(nt * 4 + ks) * 64 + lane) * 8);
      const h8v bl = *(const h8v*)(Bl_ + ((size_t)(nt * 4 + ks) * 64 + lane) * 8);
#pragma unroll
      for (int mt = 0; mt < MT_; ++mt) mfma2h(Cz[mt], A[mt], bh, bl);
    }
    {
      const int nt = 16 + w;
      const h8v bh = *(const h8v*)(Bh_ + ((size_t)(nt * 4 + ks) * 64 + lane) * 8);
      const h8v bl = *(const h8v*)(Bl_ + ((size_t)(nt * 4 + ks) * 64 + lane) * 8);
#pragma unroll
      for (int mt = 0; mt < MT_; ++mt) mfma2h(Cn[mt], A[mt], bh, bl);
    }
  }
}

// One GRU time-step for one edge segment; all resident blocks share t.
// States: pure fp16 in global (h0g/h1g), read directly as MFMA A-operands.
// LDS: h0x = new-h0 exchange (gi1 A-operand), dlo = decoder lo stash.
__global__ __launch_bounds__(512, 1) void k_gru_step(
    const unsigned short* __restrict__ h2, const int* __restrict__ ei,
    int seg_e0, int first, int last,
    const unsigned short* __restrict__ pWih0h, const unsigned short* __restrict__ pWih0l,
    const unsigned short* __restrict__ pWhh0h, const unsigned short* __restrict__ pWhh0l,
    const unsigned short* __restrict__ pWih1h, const unsigned short* __restrict__ pWih1l,
    const unsigned short* __restrict__ pWhh1h, const unsigned short* __restrict__ pWhh1l,
    const float* __restrict__ bih0, const float* __restrict__ bhh0,
    const float* __restrict__ bih1, const float* __restrict__ bhh1,
    const float* __restrict__ Wd1, const float* __restrict__ bd1,
    const float* __restrict__ Wd2, const float* __restrict__ bd2,
    unsigned short* __restrict__ h0g, unsigned short* __restrict__ h1g,
    float* __restrict__ out) {
  __shared__ unsigned short h0x[MB_ * LDP_];
  __shared__ unsigned short dlo[MB_ * LDP_];
  const int tid = threadIdx.x;
  const int lane = tid & 63, w = tid >> 6;
  const int col = lane & 15, quad = lane >> 4;
  const int mrow = lane & 15;
  const int le0 = blockIdx.x * MB_;
  const size_t ge0 = (size_t)seg_e0 + le0;
  const unsigned short* S0 = h0g + (size_t)le0 * GH_;
  const unsigned short* S1 = h1g + (size_t)le0 * GH_;

  int esrc[MT_], edst[MT_];
#pragma unroll
  for (int mt = 0; mt < MT_; ++mt) {
    esrc[mt] = ei[ge0 + mt * 16 + mrow];
    edst[mt] = ei[E_ + ge0 + mt * 16 + mrow];
  }

  const int cg = w * 16 + col;
  f4v Cr[MT_], Cz[MT_], Cin[MT_], Chn[MT_];

  // ---- layer 0 ----
#pragma unroll
  for (int mt = 0; mt < MT_; ++mt) {
    Cr[mt] = (f4v){0.f, 0.f, 0.f, 0.f};
    Cz[mt] = (f4v){0.f, 0.f, 0.f, 0.f};
    Cin[mt] = (f4v){0.f, 0.f, 0.f, 0.f};
    Chn[mt] = (f4v){0.f, 0.f, 0.f, 0.f};
  }
  mfma_pass_x(h2, esrc, edst, pWih0h, pWih0l, w, lane, Cr, Cz, Cin);
  if (!first) mfma_pass_g(S0, pWhh0h, pWhh0l, w, lane, Cr, Cz, Chn);
  __syncthreads();   // all waves' h0g reads drained before writes below
  {
    float biR = bih0[cg] + bhh0[cg];
    float biZ = bih0[128 + cg] + bhh0[128 + cg];
    float biNi = bih0[256 + cg], biNh = bhh0[256 + cg];
#pragma unroll
    for (int mt = 0; mt < MT_; ++mt)
#pragma unroll
      for (int reg = 0; reg < 4; ++reg) {
        int e = mt * 16 + quad * 4 + reg;
        float r = sigmoidf_(Cr[mt][reg] + biR);
        float z = sigmoidf_(Cz[mt][reg] + biZ);
        float n = tanhf_(Cin[mt][reg] + biNi + r * (Chn[mt][reg] + biNh));
        float hp = first ? 0.f : h2f(S0[(size_t)e * GH_ + cg]);
        float hv = (1.f - z) * n + z * hp;
        unsigned short hb = f2h(hv);
        h0g[(size_t)(le0 + e) * GH_ + cg] = hb;   // persist for next t
        h0x[e * LDP_ + cg] = hb;                  // exchange for gi1
      }
  }
  __syncthreads();   // h0x ready

  // ---- layer 1 ----
#pragma unroll
  for (int mt = 0; mt < MT_; ++mt) {
    Cr[mt] = (f4v){0.f, 0.f, 0.f, 0.f};
    Cz[mt] = (f4v){0.f, 0.f, 0.f, 0.f};
    Cin[mt] = (f4v){0.f, 0.f, 0.f, 0.f};
    Chn[mt] = (f4v){0.f, 0.f, 0.f, 0.f};
  }
  mfma_pass(h0x, pWih1h, pWih1l, w, lane, Cr, Cz, Cin);
  if (!first) mfma_pass_g(S1, pWhh1h, pWhh1l, w, lane, Cr, Cz, Chn);
  __syncthreads();   // h1g reads + h0x reads drained
  {
    float biR = bih1[cg] + bhh1[cg];
    float biZ = bih1[128 + cg] + bhh1[128 + cg];
    float biNi = bih1[256 + cg], biNh = bhh1[256 + cg];
#pragma unroll
    for (int mt = 0; mt < MT_; ++mt)
#pragma unroll
      for (int reg = 0; reg < 4; ++reg) {
        int e = mt * 16 + quad * 4 + reg;
        float r = sigmoidf_(Cr[mt][reg] + biR);
        float z = sigmoidf_(Cz[mt][reg] + biZ);
        float n = tanhf_(Cin[mt][reg] + biNi + r * (Chn[mt][reg] + biNh));
        float hp = first ? 0.f : h2f(S1[(size_t)e * GH_ + cg]);
        float hv = (1.f - z) * n + z * hp;
        if (!last) {
          h1g[(size_t)(le0 + e) * GH_ + cg] = f2h(hv);
        } else {                                   // decoder inputs: hi+lo in LDS
          unsigned short hb = f2h(hv);
          h0x[e * LDP_ + cg] = hb;
          dlo[e * LDP_ + cg] = f2h(hv - h2f(hb));
        }
      }
  }

  // ---- decoder at final t ----
  if (last) {
    __syncthreads();
    for (int ee = 0; ee < MB_ / 8; ++ee) {
      int e = w * (MB_ / 8) + ee;
      float acc = 0.f;
#pragma unroll 8
      for (int k = 0; k < GH_; ++k) {
        float hvv = h2f(h0x[e * LDP_ + k]) + h2f(dlo[e * LDP_ + k]);
        acc = fmaf(hvv, Wd1[k * 64 + lane], acc);
      }
      float rv = fmaxf(acc + bd1[lane], 0.f);
      float contrib = wave_sum(rv * Wd2[lane]);
      if (lane == 0) out[ge0 + e] = contrib + bd2[0];
    }
  }
}

// ---------------- launch ----------------
extern "C" void kernel_launch(void* const* d_in, const int* in_sizes, int n_in,
                              void* d_out, int out_size, void* d_ws, size_t ws_size,
                              hipStream_t stream) {
  (void)in_sizes; (void)n_in; (void)out_size; (void)ws_size;
  const float* x_seq = (const float*)d_in[0];
  const int*   ei    = (const int*)d_in[1];
  const float* W1    = (const float*)d_in[2];
  const float* as1   = (const float*)d_in[3];
  const float* ad1   = (const float*)d_in[4];
  const float* b1    = (const float*)d_in[5];
  const float* W2    = (const float*)d_in[6];
  const float* as2   = (const float*)d_in[7];
  const float* ad2   = (const float*)d_in[8];
  const float* b2    = (const float*)d_in[9];
  const float* Wih0  = (const float*)d_in[10];
  const float* Whh0  = (const float*)d_in[11];
  const float* bih0  = (const float*)d_in[12];
  const float* bhh0  = (const float*)d_in[13];
  const float* Wih1  = (const float*)d_in[14];
  const float* Whh1  = (const float*)d_in[15];
  const float* bih1  = (const float*)d_in[16];
  const float* bhh1  = (const float*)d_in[17];
  const float* Wd1   = (const float*)d_in[18];
  const float* bd1   = (const float*)d_in[19];
  const float* Wd2   = (const float*)d_in[20];
  const float* bd2   = (const float*)d_in[21];
  float* out = (float*)d_out;

  char* p = (char*)d_ws;
  auto alloc = [&](size_t bytes) -> char* {
    char* r = p;
    p += (bytes + 255) & ~(size_t)255;
    return r;
  };
  // persistent:
  unsigned short* h2_all = (unsigned short*)alloc((size_t)T_ * N_ * HID_ * 2);  // 20.5 MB
  unsigned short* pWih0h = (unsigned short*)alloc(NPACK_ * 2);
  unsigned short* pWih0l = (unsigned short*)alloc(NPACK_ * 2);
  unsigned short* pWhh0h = (unsigned short*)alloc(NPACK_ * 2);
  unsigned short* pWhh0l = (unsigned short*)alloc(NPACK_ * 2);
  unsigned short* pWih1h = (unsigned short*)alloc(NPACK_ * 2);
  unsigned short* pWih1l = (unsigned short*)alloc(NPACK_ * 2);
  unsigned short* pWhh1h = (unsigned short*)alloc(NPACK_ * 2);
  unsigned short* pWhh1l = (unsigned short*)alloc(NPACK_ * 2);
  int* counts   = (int*)alloc((size_t)N_ * 4);
  int* indptr   = (int*)alloc((size_t)(N_ + 1) * 4);
  int* cursors  = (int*)alloc((size_t)N_ * 4);
  int* csr      = (int*)alloc((size_t)ETOT_ * 4);
  // REGION: GAT scratch (phase 1) aliased with GRU fp16 states (phase 2).
  char* region = p;
  // GAT view (~54 MB):
  float* hlin1  = (float*)(region);
  char* q = region + (((size_t)N_ * C1_ * 4 + 255) & ~(size_t)255);
  float* h1out  = (float*)q; q += ((size_t)N_ * C1_ * 4 + 255) & ~(size_t)255;
  float* hlin2  = (float*)q; q += ((size_t)N_ * HID_ * 4 + 255) & ~(size_t)255;
  float* als1   = (float*)q; q += ((size_t)N_ * 16 + 255) & ~(size_t)255;
  float* ald1   = (float*)q; q += ((size_t)N_ * 16 + 255) & ~(size_t)255;
  float* sums1  = (float*)q; q += ((size_t)N_ * 16 + 255) & ~(size_t)255;
  float* als2   = (float*)q; q += ((size_t)N_ * 4 + 255) & ~(size_t)255;
  float* ald2   = (float*)q; q += ((size_t)N_ * 4 + 255) & ~(size_t)255;
  float* sums2  = (float*)q; q += ((size_t)N_ * 4 + 255) & ~(size_t)255;
  float* ex1    = (float*)q; q += ((size_t)ETOT_ * 16 + 255) & ~(size_t)255;
  float* ex2    = (float*)q; q += ((size_t)ETOT_ * 4 + 255) & ~(size_t)255;
  // GRU view (same region, fp16 states 2 x 20.5 MB < GAT footprint):
  unsigned short* h0g = (unsigned short*)(region);
  unsigned short* h1g = (unsigned short*)(region + (((size_t)ESEG_ * GH_ * 2 + 255) & ~(size_t)255));

  (void)hipMemsetAsync(counts, 0, (size_t)N_ * 4, stream);

  k_hist<<<(ETOT_ + 255) / 256, 256, 0, stream>>>(ei, counts);
  k_scan<<<1, 1024, 0, stream>>>(counts, indptr);
  k_copy<<<(N_ + 255) / 256, 256, 0, stream>>>(indptr, cursors);
  k_scatter<<<(ETOT_ + 255) / 256, 256, 0, stream>>>(ei, cursors, csr);
  const int pb = (NPACK_ + 255) / 256;
  k_packW16<<<pb, 256, 0, stream>>>(Wih0, pWih0h, pWih0l);
  k_packW16<<<pb, 256, 0, stream>>>(Whh0, pWhh0h, pWhh0l);
  k_packW16<<<pb, 256, 0, stream>>>(Wih1, pWih1h, pWih1l);
  k_packW16<<<pb, 256, 0, stream>>>(Whh1, pWhh1h, pWhh1l);

  for (int t = 0; t < T_; ++t) {
    const float* xt = x_seq + (size_t)t * N_ * FIN_;
    unsigned short* h2t = h2_all + (size_t)t * N_ * HID_;
    k_gat1_lin<<<N_, 256, 0, stream>>>(xt, W1, as1, ad1, hlin1, als1, ald1);
    k_gat1_attn<<<N_ / 4, 256, 0, stream>>>(csr, indptr, als1, ald1, ex1, sums1);
    k_gat1_agg<<<N_, 256, 0, stream>>>(csr, indptr, ex1, sums1, hlin1, b1, h1out);
    k_gat2_lin<<<N_ / 4, 256, 0, stream>>>(h1out, W2, as2, ad2, hlin2, als2, ald2);
    k_gat2_attn<<<N_ / 4, 256, 0, stream>>>(csr, indptr, als2, ald2, ex2, sums2);
    k_gat2_agg<<<N_ / 4, 256, 0, stream>>>(csr, indptr, ex2, sums2, hlin2, b2, h2t);
  }

  for (int seg = 0; seg < SEG_; ++seg) {
    for (int t = 0; t < T_; ++t) {
      const unsigned short* h2t = h2_all + (size_t)t * N_ * HID_;
      k_gru_step<<<ESEG_ / MB_, 512, 0, stream>>>(
          h2t, ei, seg * ESEG_, (t == 0) ? 1 : 0, (t == T_ - 1) ? 1 : 0,
          pWih0h, pWih0l, pWhh0h, pWhh0l, pWih1h, pWih1l, pWhh1h, pWhh1l,
          bih0, bhh0, bih1, bhh1, Wd1, bd1, Wd2, bd2,
          h0g, h1g, out);
    }
  }
}

// Round 13
// 5695.985 us; speedup vs baseline: 1.3519x; 1.3519x over previous
//
#include <hip/hip_runtime.h>
#include <hip/hip_fp16.h>
#include <math.h>

#define T_ 8
#define N_ 20000
#define E_ 320000
#define ETOT_ (E_ + N_)
#define FIN_ 32
#define C1_ 256   // HEADS*HID
#define HID_ 64
#define G3_ 384   // 3*GH
#define GH_ 128
#define MB_ 128   // edges per block
#define MT_ 8     // M-tiles per wave = MB_/16
#define LDP_ 136  // padded inner dim for LDS state arrays
#define SEG_ 2
#define ESEG_ (E_ / SEG_)          // 160000 edges per segment
#define NPACK_ (24 * 4 * 64 * 8)   // packed weight elems per matrix

typedef __attribute__((ext_vector_type(8))) _Float16 h8v;
typedef __attribute__((ext_vector_type(4))) float f4v;

// ---------------- helpers ----------------
__device__ __forceinline__ float wave_sum(float v) {
#pragma unroll
  for (int off = 32; off; off >>= 1) v += __shfl_down(v, off);
  return v;
}
__device__ __forceinline__ float sigmoidf_(float x) { return 1.f / (1.f + __expf(-x)); }
__device__ __forceinline__ float tanhf_(float x) {
  float e2 = __expf(2.f * x);
  return 1.f - 2.f / (e2 + 1.f);
}
__device__ __forceinline__ unsigned short f2h(float f) {
  return __half_as_ushort(__float2half_rn(f));
}
__device__ __forceinline__ float h2f(unsigned short u) {
  return __half2float(__ushort_as_half(u));
}
__device__ __forceinline__ void edge_sd(const int* ei, int e, int& s, int& d) {
  if (e < E_) { s = ei[e]; d = ei[E_ + e]; }
  else { s = e - E_; d = e - E_; }
}

// ---------------- CSR build (by dst) ----------------
__global__ void k_hist(const int* __restrict__ ei, int* __restrict__ counts) {
  int e = blockIdx.x * 256 + threadIdx.x;
  if (e >= ETOT_) return;
  int s, d; edge_sd(ei, e, s, d);
  atomicAdd(&counts[d], 1);
}

__global__ void k_scan(const int* __restrict__ counts, int* __restrict__ indptr) {
  __shared__ int tmp[1024];
  __shared__ int carry;
  int tid = threadIdx.x;
  if (tid == 0) { carry = 0; indptr[0] = 0; }
  __syncthreads();
  for (int base = 0; base < N_; base += 1024) {
    int i = base + tid;
    int v = (i < N_) ? counts[i] : 0;
    tmp[tid] = v;
    __syncthreads();
    for (int off = 1; off < 1024; off <<= 1) {
      int add = (tid >= off) ? tmp[tid - off] : 0;
      __syncthreads();
      tmp[tid] += add;
      __syncthreads();
    }
    if (i < N_) indptr[i + 1] = carry + tmp[tid];
    __syncthreads();
    if (tid == 1023) carry += tmp[1023];
    __syncthreads();
  }
}

__global__ void k_copy(const int* __restrict__ indptr, int* __restrict__ cursors) {
  int i = blockIdx.x * 256 + threadIdx.x;
  if (i < N_) cursors[i] = indptr[i];
}

__global__ void k_scatter(const int* __restrict__ ei, int* __restrict__ cursors,
                          int* __restrict__ csr_src) {
  int e = blockIdx.x * 256 + threadIdx.x;
  if (e >= ETOT_) return;
  int s, d; edge_sd(ei, e, s, d);
  int pos = atomicAdd(&cursors[d], 1);
  csr_src[pos] = s;
}

// ---------------- weight pack: W[384][128] fp32 -> B-fragment-ordered fp16 hi/lo ----
__global__ void k_packW16(const float* __restrict__ W, unsigned short* __restrict__ Bh,
                          unsigned short* __restrict__ Bl) {
  int idx = blockIdx.x * 256 + threadIdx.x;
  if (idx >= NPACK_) return;
  int j = idx & 7, lane = (idx >> 3) & 63, ks = (idx >> 9) & 3, nt = idx >> 11;
  int n = nt * 16 + (lane & 15);
  int k = ks * 32 + (lane >> 4) * 8 + j;
  float v = W[n * GH_ + k];
  unsigned short h = f2h(v);
  Bh[idx] = h;
  Bl[idx] = f2h(v - h2f(h));
}

// ---------------- GAT layer 1 ----------------
__global__ __launch_bounds__(256) void k_gat1_lin(
    const float* __restrict__ x, const float* __restrict__ W1,
    const float* __restrict__ as1, const float* __restrict__ ad1,
    float* __restrict__ hlin, float* __restrict__ als, float* __restrict__ ald) {
  int n = blockIdx.x;
  int j = threadIdx.x;
  __shared__ float sx[FIN_];
  if (j < FIN_) sx[j] = x[n * FIN_ + j];
  __syncthreads();
  float acc = 0.f;
#pragma unroll
  for (int k = 0; k < FIN_; ++k) acc = fmaf(sx[k], W1[k * C1_ + j], acc);
  hlin[(size_t)n * C1_ + j] = acc;
  int h = j >> 6, c = j & 63;
  float vs = wave_sum(acc * as1[h * 64 + c]);
  float vd = wave_sum(acc * ad1[h * 64 + c]);
  if (c == 0) { als[n * 4 + h] = vs; ald[n * 4 + h] = vd; }
}

__global__ __launch_bounds__(256) void k_gat1_attn(
    const int* __restrict__ csr_src, const int* __restrict__ indptr,
    const float* __restrict__ als, const float* __restrict__ ald,
    float* __restrict__ ex, float* __restrict__ sums) {
  int w = threadIdx.x >> 6, lane = threadIdx.x & 63;
  int n = blockIdx.x * 4 + w;
  int s0 = indptr[n], s1 = indptr[n + 1];
  float adv[4], mx[4], sm[4];
#pragma unroll
  for (int h = 0; h < 4; ++h) { adv[h] = ald[n * 4 + h]; mx[h] = -1e30f; sm[h] = 0.f; }
  for (int e = s0 + lane; e < s1; e += 64) {
    int s = csr_src[e];
#pragma unroll
    for (int h = 0; h < 4; ++h) {
      float sc = als[s * 4 + h] + adv[h];
      sc = sc >= 0.f ? sc : 0.2f * sc;
      ex[(size_t)e * 4 + h] = sc;
      mx[h] = fmaxf(mx[h], sc);
    }
  }
#pragma unroll
  for (int h = 0; h < 4; ++h) {
#pragma unroll
    for (int off = 32; off; off >>= 1) mx[h] = fmaxf(mx[h], __shfl_xor(mx[h], off));
  }
  for (int e = s0 + lane; e < s1; e += 64) {
#pragma unroll
    for (int h = 0; h < 4; ++h) {
      float v = __expf(ex[(size_t)e * 4 + h] - mx[h]);
      ex[(size_t)e * 4 + h] = v;
      sm[h] += v;
    }
  }
#pragma unroll
  for (int h = 0; h < 4; ++h) sm[h] = wave_sum(sm[h]);
  if (lane == 0) {
#pragma unroll
    for (int h = 0; h < 4; ++h) sums[n * 4 + h] = sm[h];
  }
}

__global__ __launch_bounds__(256) void k_gat1_agg(
    const int* __restrict__ csr_src, const int* __restrict__ indptr,
    const float* __restrict__ ex, const float* __restrict__ sums,
    const float* __restrict__ hlin, const float* __restrict__ b1,
    float* __restrict__ h1out) {
  int n = blockIdx.x;
  int j = threadIdx.x;
  int hh = j >> 6;
  int s0 = indptr[n], s1 = indptr[n + 1];
  float inv = 1.f / (sums[n * 4 + hh] + 1e-16f);
  float acc = 0.f;
  for (int e = s0; e < s1; ++e) {
    int s = csr_src[e];
    float a = ex[(size_t)e * 4 + hh] * inv;
    acc = fmaf(a, hlin[(size_t)s * C1_ + j], acc);
  }
  float o = acc + b1[j];
  h1out[(size_t)n * C1_ + j] = o > 0.f ? o : expm1f(o);
}

// ---------------- GAT layer 2 ----------------
__global__ __launch_bounds__(256) void k_gat2_lin(
    const float* __restrict__ h1out, const float* __restrict__ W2,
    const float* __restrict__ as2, const float* __restrict__ ad2,
    float* __restrict__ hlin2, float* __restrict__ als, float* __restrict__ ald) {
  int w = threadIdx.x >> 6, lane = threadIdx.x & 63;
  int n = blockIdx.x * 4 + w;
  __shared__ float sx[4][C1_];
  for (int k = lane; k < C1_; k += 64) sx[w][k] = h1out[(size_t)n * C1_ + k];
  __syncthreads();
  float acc = 0.f;
#pragma unroll 4
  for (int k = 0; k < C1_; ++k) acc = fmaf(sx[w][k], W2[k * HID_ + lane], acc);
  hlin2[(size_t)n * HID_ + lane] = acc;
  float vs = wave_sum(acc * as2[lane]);
  float vd = wave_sum(acc * ad2[lane]);
  if (lane == 0) { als[n] = vs; ald[n] = vd; }
}

__global__ __launch_bounds__(256) void k_gat2_attn(
    const int* __restrict__ csr_src, const int* __restrict__ indptr,
    const float* __restrict__ als, const float* __restrict__ ald,
    float* __restrict__ ex, float* __restrict__ sums) {
  int w = threadIdx.x >> 6, lane = threadIdx.x & 63;
  int n = blockIdx.x * 4 + w;
  int s0 = indptr[n], s1 = indptr[n + 1];
  float adv = ald[n];
  float mx = -1e30f, sm = 0.f;
  for (int e = s0 + lane; e < s1; e += 64) {
    float sc = als[csr_src[e]] + adv;
    sc = sc >= 0.f ? sc : 0.2f * sc;
    ex[e] = sc;
    mx = fmaxf(mx, sc);
  }
#pragma unroll
  for (int off = 32; off; off >>= 1) mx = fmaxf(mx, __shfl_xor(mx, off));
  for (int e = s0 + lane; e < s1; e += 64) {
    float v = __expf(ex[e] - mx);
    ex[e] = v;
    sm += v;
  }
  sm = wave_sum(sm);
  if (lane == 0) sums[n] = sm;
}

// writes h2 as fp16 (A-operand of the layer-0 input MFMA)
__global__ __launch_bounds__(256) void k_gat2_agg(
    const int* __restrict__ csr_src, const int* __restrict__ indptr,
    const float* __restrict__ ex, const float* __restrict__ sums,
    const float* __restrict__ hlin2, const float* __restrict__ b2,
    unsigned short* __restrict__ h2f16) {
  int w = threadIdx.x >> 6, lane = threadIdx.x & 63;
  int n = blockIdx.x * 4 + w;
  int s0 = indptr[n], s1 = indptr[n + 1];
  float inv = 1.f / (sums[n] + 1e-16f);
  float acc = 0.f;
  for (int e = s0; e < s1; ++e) {
    int s = csr_src[e];
    acc = fmaf(ex[e] * inv, hlin2[(size_t)s * HID_ + lane], acc);
  }
  h2f16[(size_t)n * HID_ + lane] = f2h(acc + b2[lane]);
}

// ---------------- MFMA GRU step (t-outer, fp16 states, LDS-only epilogues) ----
// fp16x2: C += A*(Bh+Bl); A single fp16, W split fp16 hi/lo
__device__ __forceinline__ void mfma2h(f4v& acc, h8v a, h8v bh, h8v bl) {
  acc = __builtin_amdgcn_mfma_f32_16x16x32_f16(a, bh, acc, 0, 0, 0);
  acc = __builtin_amdgcn_mfma_f32_16x16x32_f16(a, bl, acc, 0, 0, 0);
}

// LDS state pass: wave w owns one 16-col N-tile per gate (r: w, z: 8+w, n: 16+w)
__device__ __forceinline__ void mfma_pass(
    const unsigned short* A_,
    const unsigned short* __restrict__ Bh_, const unsigned short* __restrict__ Bl_,
    int w, int lane, f4v Cr[MT_], f4v Cz[MT_], f4v Cn[MT_]) {
  const int mrow = lane & 15, quad = lane >> 4;
#pragma unroll
  for (int ks = 0; ks < 4; ++ks) {
    h8v A[MT_];
    const int aoff = mrow * LDP_ + ks * 32 + quad * 8;
#pragma unroll
    for (int mt = 0; mt < MT_; ++mt) A[mt] = *(const h8v*)(A_ + aoff + mt * (16 * LDP_));
    {
      const int nt = w;
      const h8v bh = *(const h8v*)(Bh_ + ((size_t)(nt * 4 + ks) * 64 + lane) * 8);
      const h8v bl = *(const h8v*)(Bl_ + ((size_t)(nt * 4 + ks) * 64 + lane) * 8);
#pragma unroll
      for (int mt = 0; mt < MT_; ++mt) mfma2h(Cr[mt], A[mt], bh, bl);
    }
    {
      const int nt = 8 + w;
      const h8v bh = *(const h8v*)(Bh_ + ((size_t)(nt * 4 + ks) * 64 + lane) * 8);
      const h8v bl = *(const h8v*)(Bl_ + ((size_t)(nt * 4 + ks) * 64 + lane) * 8);
#pragma unroll
      for (int mt = 0; mt < MT_; ++mt) mfma2h(Cz[mt], A[mt], bh, bl);
    }
    {
      const int nt = 16 + w;
      const h8v bh = *(const h8v*)(Bh_ + ((size_t)(nt * 4 + ks) * 64 + lane) * 8);
      const h8v bl = *(const h8v*)(Bl_ + ((size_t)(nt * 4 + ks) * 64 + lane) * 8);
#pragma unroll
      for (int mt = 0; mt < MT_; ++mt) mfma2h(Cn[mt], A[mt], bh, bl);
    }
  }
}

// X pass (gi0): A from h2 slice, node-gathered (single-t slice -> L2-hot)
__device__ __forceinline__ void mfma_pass_x(
    const unsigned short* __restrict__ h2,
    const int esrc[MT_], const int edst[MT_],
    const unsigned short* __restrict__ Bh_, const unsigned short* __restrict__ Bl_,
    int w, int lane, f4v Cr[MT_], f4v Cz[MT_], f4v Cn[MT_]) {
  const int quad = lane >> 4;
#pragma unroll
  for (int ks = 0; ks < 4; ++ks) {
    h8v A[MT_];
    const int choff = (ks & 1) * 32 + quad * 8;
#pragma unroll
    for (int mt = 0; mt < MT_; ++mt) {
      const int node = (ks < 2) ? esrc[mt] : edst[mt];
      A[mt] = *(const h8v*)(h2 + (size_t)node * HID_ + choff);
    }
    {
      const int nt = w;
      const h8v bh = *(const h8v*)(Bh_ + ((size_t)(nt * 4 + ks) * 64 + lane) * 8);
      const h8v bl = *(const h8v*)(Bl_ + ((size_t)(nt * 4 + ks) * 64 + lane) * 8);
#pragma unroll
      for (int mt = 0; mt < MT_; ++mt) mfma2h(Cr[mt], A[mt], bh, bl);
    }
    {
      const int nt = 8 + w;
      const h8v bh = *(const h8v*)(Bh_ + ((size_t)(nt * 4 + ks) * 64 + lane) * 8);
      const h8v bl = *(const h8v*)(Bl_ + ((size_t)(nt * 4 + ks) * 64 + lane) * 8);
#pragma unroll
      for (int mt = 0; mt < MT_; ++mt) mfma2h(Cz[mt], A[mt], bh, bl);
    }
    {
      const int nt = 16 + w;
      const h8v bh = *(const h8v*)(Bh_ + ((size_t)(nt * 4 + ks) * 64 + lane) * 8);
      const h8v bl = *(const h8v*)(Bl_ + ((size_t)(nt * 4 + ks) * 64 + lane) * 8);
#pragma unroll
      for (int mt = 0; mt < MT_; ++mt) mfma2h(Cn[mt], A[mt], bh, bl);
    }
  }
}

// One GRU time-step for one edge segment; all resident blocks share t.
// fp16 states staged LDS<->global with pure 16B copies; epilogues write LDS
// only; the single coalesced global flush happens after the LAST barrier so
// no mid-kernel barrier waits on scattered global stores.
__global__ __launch_bounds__(512, 1) void k_gru_step(
    const unsigned short* __restrict__ h2, const int* __restrict__ ei,
    int seg_e0, int first, int last,
    const unsigned short* __restrict__ pWih0h, const unsigned short* __restrict__ pWih0l,
    const unsigned short* __restrict__ pWhh0h, const unsigned short* __restrict__ pWhh0l,
    const unsigned short* __restrict__ pWih1h, const unsigned short* __restrict__ pWih1l,
    const unsigned short* __restrict__ pWhh1h, const unsigned short* __restrict__ pWhh1l,
    const float* __restrict__ bih0, const float* __restrict__ bhh0,
    const float* __restrict__ bih1, const float* __restrict__ bhh1,
    const float* __restrict__ Wd1, const float* __restrict__ bd1,
    const float* __restrict__ Wd2, const float* __restrict__ bd2,
    unsigned short* __restrict__ h0g, unsigned short* __restrict__ h1g,
    float* __restrict__ out) {
  __shared__ unsigned short h0h[MB_ * LDP_];
  __shared__ unsigned short h1h[MB_ * LDP_];
  const int tid = threadIdx.x;
  const int lane = tid & 63, w = tid >> 6;
  const int col = lane & 15, quad = lane >> 4;
  const int mrow = lane & 15;
  const int le0 = blockIdx.x * MB_;
  const size_t ge0 = (size_t)seg_e0 + le0;

  // ---- stage fp16 states global -> LDS (pure 16B copies, bulk-issued) ----
  if (!first) {
    for (int i = tid; i < MB_ * 16; i += 512) {
      int e = i >> 4, c = (i & 15) * 8;
      *(h8v*)&h0h[e * LDP_ + c] = *(const h8v*)(h0g + (size_t)(le0 + e) * GH_ + c);
      *(h8v*)&h1h[e * LDP_ + c] = *(const h8v*)(h1g + (size_t)(le0 + e) * GH_ + c);
    }
  }
  int esrc[MT_], edst[MT_];
#pragma unroll
  for (int mt = 0; mt < MT_; ++mt) {
    esrc[mt] = ei[ge0 + mt * 16 + mrow];
    edst[mt] = ei[E_ + ge0 + mt * 16 + mrow];
  }
  __syncthreads();

  const int cg = w * 16 + col;
  f4v Cr[MT_], Cz[MT_], Cin[MT_], Chn[MT_];

  // ---- layer 0 ----
#pragma unroll
  for (int mt = 0; mt < MT_; ++mt) {
    Cr[mt] = (f4v){0.f, 0.f, 0.f, 0.f};
    Cz[mt] = (f4v){0.f, 0.f, 0.f, 0.f};
    Cin[mt] = (f4v){0.f, 0.f, 0.f, 0.f};
    Chn[mt] = (f4v){0.f, 0.f, 0.f, 0.f};
  }
  mfma_pass_x(h2, esrc, edst, pWih0h, pWih0l, w, lane, Cr, Cz, Cin);
  if (!first) mfma_pass(h0h, pWhh0h, pWhh0l, w, lane, Cr, Cz, Chn);
  __syncthreads();   // all gh0 reads of old h0h done (LDS drain only)
  {
    float biR = bih0[cg] + bhh0[cg];
    float biZ = bih0[128 + cg] + bhh0[128 + cg];
    float biNi = bih0[256 + cg], biNh = bhh0[256 + cg];
#pragma unroll
    for (int mt = 0; mt < MT_; ++mt)
#pragma unroll
      for (int reg = 0; reg < 4; ++reg) {
        int e = mt * 16 + quad * 4 + reg;
        float r = sigmoidf_(Cr[mt][reg] + biR);
        float z = sigmoidf_(Cz[mt][reg] + biZ);
        float n = tanhf_(Cin[mt][reg] + biNi + r * (Chn[mt][reg] + biNh));
        float hp = first ? 0.f : h2f(h0h[e * LDP_ + cg]);   // own slot
        float hv = (1.f - z) * n + z * hp;
        h0h[e * LDP_ + cg] = f2h(hv);                       // new h0 (LDS only)
      }
  }
  __syncthreads();   // new h0h visible

  // ---- layer 1 ----
#pragma unroll
  for (int mt = 0; mt < MT_; ++mt) {
    Cr[mt] = (f4v){0.f, 0.f, 0.f, 0.f};
    Cz[mt] = (f4v){0.f, 0.f, 0.f, 0.f};
    Cin[mt] = (f4v){0.f, 0.f, 0.f, 0.f};
    Chn[mt] = (f4v){0.f, 0.f, 0.f, 0.f};
  }
  mfma_pass(h0h, pWih1h, pWih1l, w, lane, Cr, Cz, Cin);
  if (!first) mfma_pass(h1h, pWhh1h, pWhh1l, w, lane, Cr, Cz, Chn);
  __syncthreads();   // old h1h reads done
  {
    float biR = bih1[cg] + bhh1[cg];
    float biZ = bih1[128 + cg] + bhh1[128 + cg];
    float biNi = bih1[256 + cg], biNh = bhh1[256 + cg];
#pragma unroll
    for (int mt = 0; mt < MT_; ++mt)
#pragma unroll
      for (int reg = 0; reg < 4; ++reg) {
        int e = mt * 16 + quad * 4 + reg;
        float r = sigmoidf_(Cr[mt][reg] + biR);
        float z = sigmoidf_(Cz[mt][reg] + biZ);
        float n = tanhf_(Cin[mt][reg] + biNi + r * (Chn[mt][reg] + biNh));
        float hp = first ? 0.f : h2f(h1h[e * LDP_ + cg]);
        float hv = (1.f - z) * n + z * hp;
        if (!last) {
          h1h[e * LDP_ + cg] = f2h(hv);              // LDS only
        } else {                                     // decoder hi/lo stash
          unsigned short hb = f2h(hv);
          h1h[e * LDP_ + cg] = hb;
          h0h[e * LDP_ + cg] = f2h(hv - h2f(hb));    // h0h no longer needed
        }
      }
  }
  __syncthreads();

  if (!last) {
    // ---- single coalesced flush LDS -> global (after last barrier) ----
    for (int i = tid; i < MB_ * 16; i += 512) {
      int e = i >> 4, c = (i & 15) * 8;
      *(h8v*)(h0g + (size_t)(le0 + e) * GH_ + c) = *(const h8v*)&h0h[e * LDP_ + c];
      *(h8v*)(h1g + (size_t)(le0 + e) * GH_ + c) = *(const h8v*)&h1h[e * LDP_ + c];
    }
  } else {
    // ---- decoder: out = relu(h1 @ Wd1 + bd1) @ Wd2 + bd2 ----
    for (int ee = 0; ee < MB_ / 8; ++ee) {
      int e = w * (MB_ / 8) + ee;
      float acc = 0.f;
#pragma unroll 8
      for (int k = 0; k < GH_; ++k) {
        float hvv = h2f(h1h[e * LDP_ + k]) + h2f(h0h[e * LDP_ + k]);
        acc = fmaf(hvv, Wd1[k * 64 + lane], acc);
      }
      float rv = fmaxf(acc + bd1[lane], 0.f);
      float contrib = wave_sum(rv * Wd2[lane]);
      if (lane == 0) out[ge0 + e] = contrib + bd2[0];
    }
  }
}

// ---------------- launch ----------------
extern "C" void kernel_launch(void* const* d_in, const int* in_sizes, int n_in,
                              void* d_out, int out_size, void* d_ws, size_t ws_size,
                              hipStream_t stream) {
  (void)in_sizes; (void)n_in; (void)out_size; (void)ws_size;
  const float* x_seq = (const float*)d_in[0];
  const int*   ei    = (const int*)d_in[1];
  const float* W1    = (const float*)d_in[2];
  const float* as1   = (const float*)d_in[3];
  const float* ad1   = (const float*)d_in[4];
  const float* b1    = (const float*)d_in[5];
  const float* W2    = (const float*)d_in[6];
  const float* as2   = (const float*)d_in[7];
  const float* ad2   = (const float*)d_in[8];
  const float* b2    = (const float*)d_in[9];
  const float* Wih0  = (const float*)d_in[10];
  const float* Whh0  = (const float*)d_in[11];
  const float* bih0  = (const float*)d_in[12];
  const float* bhh0  = (const float*)d_in[13];
  const float* Wih1  = (const float*)d_in[14];
  const float* Whh1  = (const float*)d_in[15];
  const float* bih1  = (const float*)d_in[16];
  const float* bhh1  = (const float*)d_in[17];
  const float* Wd1   = (const float*)d_in[18];
  const float* bd1   = (const float*)d_in[19];
  const float* Wd2   = (const float*)d_in[20];
  const float* bd2   = (const float*)d_in[21];
  float* out = (float*)d_out;

  char* p = (char*)d_ws;
  auto alloc = [&](size_t bytes) -> char* {
    char* r = p;
    p += (bytes + 255) & ~(size_t)255;
    return r;
  };
  // persistent:
  unsigned short* h2_all = (unsigned short*)alloc((size_t)T_ * N_ * HID_ * 2);  // 20.5 MB
  unsigned short* pWih0h = (unsigned short*)alloc(NPACK_ * 2);
  unsigned short* pWih0l = (unsigned short*)alloc(NPACK_ * 2);
  unsigned short* pWhh0h = (unsigned short*)alloc(NPACK_ * 2);
  unsigned short* pWhh0l = (unsigned short*)alloc(NPACK_ * 2);
  unsigned short* pWih1h = (unsigned short*)alloc(NPACK_ * 2);
  unsigned short* pWih1l = (unsigned short*)alloc(NPACK_ * 2);
  unsigned short* pWhh1h = (unsigned short*)alloc(NPACK_ * 2);
  unsigned short* pWhh1l = (unsigned short*)alloc(NPACK_ * 2);
  int* counts   = (int*)alloc((size_t)N_ * 4);
  int* indptr   = (int*)alloc((size_t)(N_ + 1) * 4);
  int* cursors  = (int*)alloc((size_t)N_ * 4);
  int* csr      = (int*)alloc((size_t)ETOT_ * 4);
  // REGION: GAT scratch (phase 1) aliased with GRU fp16 states (phase 2).
  char* region = p;
  // GAT view (~70 MB):
  float* hlin1  = (float*)(region);
  char* q = region + (((size_t)N_ * C1_ * 4 + 255) & ~(size_t)255);
  float* h1out  = (float*)q; q += ((size_t)N_ * C1_ * 4 + 255) & ~(size_t)255;
  float* hlin2  = (float*)q; q += ((size_t)N_ * HID_ * 4 + 255) & ~(size_t)255;
  float* als1   = (float*)q; q += ((size_t)N_ * 16 + 255) & ~(size_t)255;
  float* ald1   = (float*)q; q += ((size_t)N_ * 16 + 255) & ~(size_t)255;
  float* sums1  = (float*)q; q += ((size_t)N_ * 16 + 255) & ~(size_t)255;
  float* als2   = (float*)q; q += ((size_t)N_ * 4 + 255) & ~(size_t)255;
  float* ald2   = (float*)q; q += ((size_t)N_ * 4 + 255) & ~(size_t)255;
  float* sums2  = (float*)q; q += ((size_t)N_ * 4 + 255) & ~(size_t)255;
  float* ex1    = (float*)q; q += ((size_t)ETOT_ * 16 + 255) & ~(size_t)255;
  float* ex2    = (float*)q; q += ((size_t)ETOT_ * 4 + 255) & ~(size_t)255;
  // GRU view (same region): fp16 states 2 x 41 MB = 82 MB
  unsigned short* h0g = (unsigned short*)(region);
  unsigned short* h1g = (unsigned short*)(region + (((size_t)ESEG_ * GH_ * 2 + 255) & ~(size_t)255));

  (void)hipMemsetAsync(counts, 0, (size_t)N_ * 4, stream);

  k_hist<<<(ETOT_ + 255) / 256, 256, 0, stream>>>(ei, counts);
  k_scan<<<1, 1024, 0, stream>>>(counts, indptr);
  k_copy<<<(N_ + 255) / 256, 256, 0, stream>>>(indptr, cursors);
  k_scatter<<<(ETOT_ + 255) / 256, 256, 0, stream>>>(ei, cursors, csr);
  const int pb = (NPACK_ + 255) / 256;
  k_packW16<<<pb, 256, 0, stream>>>(Wih0, pWih0h, pWih0l);
  k_packW16<<<pb, 256, 0, stream>>>(Whh0, pWhh0h, pWhh0l);
  k_packW16<<<pb, 256, 0, stream>>>(Wih1, pWih1h, pWih1l);
  k_packW16<<<pb, 256, 0, stream>>>(Whh1, pWhh1h, pWhh1l);

  for (int t = 0; t < T_; ++t) {
    const float* xt = x_seq + (size_t)t * N_ * FIN_;
    unsigned short* h2t = h2_all + (size_t)t * N_ * HID_;
    k_gat1_lin<<<N_, 256, 0, stream>>>(xt, W1, as1, ad1, hlin1, als1, ald1);
    k_gat1_attn<<<N_ / 4, 256, 0, stream>>>(csr, indptr, als1, ald1, ex1, sums1);
    k_gat1_agg<<<N_, 256, 0, stream>>>(csr, indptr, ex1, sums1, hlin1, b1, h1out);
    k_gat2_lin<<<N_ / 4, 256, 0, stream>>>(h1out, W2, as2, ad2, hlin2, als2, ald2);
    k_gat2_attn<<<N_ / 4, 256, 0, stream>>>(csr, indptr, als2, ald2, ex2, sums2);
    k_gat2_agg<<<N_ / 4, 256, 0, stream>>>(csr, indptr, ex2, sums2, hlin2, b2, h2t);
  }

  for (int seg = 0; seg < SEG_; ++seg) {
    for (int t = 0; t < T_; ++t) {
      const unsigned short* h2t = h2_all + (size_t)t * N_ * HID_;
      k_gru_step<<<ESEG_ / MB_, 512, 0, stream>>>(
          h2t, ei, seg * ESEG_, (t == 0) ? 1 : 0, (t == T_ - 1) ? 1 : 0,
          pWih0h, pWih0l, pWhh0h, pWhh0l, pWih1h, pWih1l, pWhh1h, pWhh1l,
          bih0, bhh0, bih1, bhh1, Wd1, bd1, Wd2, bd2,
          h0g, h1g, out);
    }
  }
}

// Round 14
// 5480.317 us; speedup vs baseline: 1.4051x; 1.0394x over previous
//
#include <hip/hip_runtime.h>
#include <hip/hip_fp16.h>
#include <math.h>

#define T_ 8
#define N_ 20000
#define E_ 320000
#define ETOT_ (E_ + N_)
#define FIN_ 32
#define C1_ 256   // HEADS*HID
#define HID_ 64
#define G3_ 384   // 3*GH
#define GH_ 128
#define MB_ 64    // edges per block (small acc file -> 4 waves/SIMD)
#define MT_ 4     // M-tiles per wave = MB_/16
#define LDP_ 136  // padded inner dim for LDS state arrays
#define SEG_ 2
#define ESEG_ (E_ / SEG_)          // 160000 edges per segment
#define NPACK_ (24 * 4 * 64 * 8)   // packed weight elems per matrix

typedef __attribute__((ext_vector_type(8))) _Float16 h8v;
typedef __attribute__((ext_vector_type(4))) float f4v;

// ---------------- helpers ----------------
__device__ __forceinline__ float wave_sum(float v) {
#pragma unroll
  for (int off = 32; off; off >>= 1) v += __shfl_down(v, off);
  return v;
}
__device__ __forceinline__ float sigmoidf_(float x) { return 1.f / (1.f + __expf(-x)); }
__device__ __forceinline__ float tanhf_(float x) {
  float e2 = __expf(2.f * x);
  return 1.f - 2.f / (e2 + 1.f);
}
__device__ __forceinline__ unsigned short f2h(float f) {
  return __half_as_ushort(__float2half_rn(f));
}
__device__ __forceinline__ float h2f(unsigned short u) {
  return __half2float(__ushort_as_half(u));
}
__device__ __forceinline__ void edge_sd(const int* ei, int e, int& s, int& d) {
  if (e < E_) { s = ei[e]; d = ei[E_ + e]; }
  else { s = e - E_; d = e - E_; }
}

// ---------------- CSR build (by dst) ----------------
__global__ void k_hist(const int* __restrict__ ei, int* __restrict__ counts) {
  int e = blockIdx.x * 256 + threadIdx.x;
  if (e >= ETOT_) return;
  int s, d; edge_sd(ei, e, s, d);
  atomicAdd(&counts[d], 1);
}

__global__ void k_scan(const int* __restrict__ counts, int* __restrict__ indptr) {
  __shared__ int tmp[1024];
  __shared__ int carry;
  int tid = threadIdx.x;
  if (tid == 0) { carry = 0; indptr[0] = 0; }
  __syncthreads();
  for (int base = 0; base < N_; base += 1024) {
    int i = base + tid;
    int v = (i < N_) ? counts[i] : 0;
    tmp[tid] = v;
    __syncthreads();
    for (int off = 1; off < 1024; off <<= 1) {
      int add = (tid >= off) ? tmp[tid - off] : 0;
      __syncthreads();
      tmp[tid] += add;
      __syncthreads();
    }
    if (i < N_) indptr[i + 1] = carry + tmp[tid];
    __syncthreads();
    if (tid == 1023) carry += tmp[1023];
    __syncthreads();
  }
}

__global__ void k_copy(const int* __restrict__ indptr, int* __restrict__ cursors) {
  int i = blockIdx.x * 256 + threadIdx.x;
  if (i < N_) cursors[i] = indptr[i];
}

__global__ void k_scatter(const int* __restrict__ ei, int* __restrict__ cursors,
                          int* __restrict__ csr_src) {
  int e = blockIdx.x * 256 + threadIdx.x;
  if (e >= ETOT_) return;
  int s, d; edge_sd(ei, e, s, d);
  int pos = atomicAdd(&cursors[d], 1);
  csr_src[pos] = s;
}

// ---------------- weight pack: W[384][128] fp32 -> B-fragment-ordered fp16 hi/lo ----
__global__ void k_packW16(const float* __restrict__ W, unsigned short* __restrict__ Bh,
                          unsigned short* __restrict__ Bl) {
  int idx = blockIdx.x * 256 + threadIdx.x;
  if (idx >= NPACK_) return;
  int j = idx & 7, lane = (idx >> 3) & 63, ks = (idx >> 9) & 3, nt = idx >> 11;
  int n = nt * 16 + (lane & 15);
  int k = ks * 32 + (lane >> 4) * 8 + j;
  float v = W[n * GH_ + k];
  unsigned short h = f2h(v);
  Bh[idx] = h;
  Bl[idx] = f2h(v - h2f(h));
}

// ---------------- GAT layer 1 ----------------
__global__ __launch_bounds__(256) void k_gat1_lin(
    const float* __restrict__ x, const float* __restrict__ W1,
    const float* __restrict__ as1, const float* __restrict__ ad1,
    float* __restrict__ hlin, float* __restrict__ als, float* __restrict__ ald) {
  int n = blockIdx.x;
  int j = threadIdx.x;
  __shared__ float sx[FIN_];
  if (j < FIN_) sx[j] = x[n * FIN_ + j];
  __syncthreads();
  float acc = 0.f;
#pragma unroll
  for (int k = 0; k < FIN_; ++k) acc = fmaf(sx[k], W1[k * C1_ + j], acc);
  hlin[(size_t)n * C1_ + j] = acc;
  int h = j >> 6, c = j & 63;
  float vs = wave_sum(acc * as1[h * 64 + c]);
  float vd = wave_sum(acc * ad1[h * 64 + c]);
  if (c == 0) { als[n * 4 + h] = vs; ald[n * 4 + h] = vd; }
}

__global__ __launch_bounds__(256) void k_gat1_attn(
    const int* __restrict__ csr_src, const int* __restrict__ indptr,
    const float* __restrict__ als, const float* __restrict__ ald,
    float* __restrict__ ex, float* __restrict__ sums) {
  int w = threadIdx.x >> 6, lane = threadIdx.x & 63;
  int n = blockIdx.x * 4 + w;
  int s0 = indptr[n], s1 = indptr[n + 1];
  float adv[4], mx[4], sm[4];
#pragma unroll
  for (int h = 0; h < 4; ++h) { adv[h] = ald[n * 4 + h]; mx[h] = -1e30f; sm[h] = 0.f; }
  for (int e = s0 + lane; e < s1; e += 64) {
    int s = csr_src[e];
#pragma unroll
    for (int h = 0; h < 4; ++h) {
      float sc = als[s * 4 + h] + adv[h];
      sc = sc >= 0.f ? sc : 0.2f * sc;
      ex[(size_t)e * 4 + h] = sc;
      mx[h] = fmaxf(mx[h], sc);
    }
  }
#pragma unroll
  for (int h = 0; h < 4; ++h) {
#pragma unroll
    for (int off = 32; off; off >>= 1) mx[h] = fmaxf(mx[h], __shfl_xor(mx[h], off));
  }
  for (int e = s0 + lane; e < s1; e += 64) {
#pragma unroll
    for (int h = 0; h < 4; ++h) {
      float v = __expf(ex[(size_t)e * 4 + h] - mx[h]);
      ex[(size_t)e * 4 + h] = v;
      sm[h] += v;
    }
  }
#pragma unroll
  for (int h = 0; h < 4; ++h) sm[h] = wave_sum(sm[h]);
  if (lane == 0) {
#pragma unroll
    for (int h = 0; h < 4; ++h) sums[n * 4 + h] = sm[h];
  }
}

__global__ __launch_bounds__(256) void k_gat1_agg(
    const int* __restrict__ csr_src, const int* __restrict__ indptr,
    const float* __restrict__ ex, const float* __restrict__ sums,
    const float* __restrict__ hlin, const float* __restrict__ b1,
    float* __restrict__ h1out) {
  int n = blockIdx.x;
  int j = threadIdx.x;
  int hh = j >> 6;
  int s0 = indptr[n], s1 = indptr[n + 1];
  float inv = 1.f / (sums[n * 4 + hh] + 1e-16f);
  float acc = 0.f;
  for (int e = s0; e < s1; ++e) {
    int s = csr_src[e];
    float a = ex[(size_t)e * 4 + hh] * inv;
    acc = fmaf(a, hlin[(size_t)s * C1_ + j], acc);
  }
  float o = acc + b1[j];
  h1out[(size_t)n * C1_ + j] = o > 0.f ? o : expm1f(o);
}

// ---------------- GAT layer 2 ----------------
__global__ __launch_bounds__(256) void k_gat2_lin(
    const float* __restrict__ h1out, const float* __restrict__ W2,
    const float* __restrict__ as2, const float* __restrict__ ad2,
    float* __restrict__ hlin2, float* __restrict__ als, float* __restrict__ ald) {
  int w = threadIdx.x >> 6, lane = threadIdx.x & 63;
  int n = blockIdx.x * 4 + w;
  __shared__ float sx[4][C1_];
  for (int k = lane; k < C1_; k += 64) sx[w][k] = h1out[(size_t)n * C1_ + k];
  __syncthreads();
  float acc = 0.f;
#pragma unroll 4
  for (int k = 0; k < C1_; ++k) acc = fmaf(sx[w][k], W2[k * HID_ + lane], acc);
  hlin2[(size_t)n * HID_ + lane] = acc;
  float vs = wave_sum(acc * as2[lane]);
  float vd = wave_sum(acc * ad2[lane]);
  if (lane == 0) { als[n] = vs; ald[n] = vd; }
}

__global__ __launch_bounds__(256) void k_gat2_attn(
    const int* __restrict__ csr_src, const int* __restrict__ indptr,
    const float* __restrict__ als, const float* __restrict__ ald,
    float* __restrict__ ex, float* __restrict__ sums) {
  int w = threadIdx.x >> 6, lane = threadIdx.x & 63;
  int n = blockIdx.x * 4 + w;
  int s0 = indptr[n], s1 = indptr[n + 1];
  float adv = ald[n];
  float mx = -1e30f, sm = 0.f;
  for (int e = s0 + lane; e < s1; e += 64) {
    float sc = als[csr_src[e]] + adv;
    sc = sc >= 0.f ? sc : 0.2f * sc;
    ex[e] = sc;
    mx = fmaxf(mx, sc);
  }
#pragma unroll
  for (int off = 32; off; off >>= 1) mx = fmaxf(mx, __shfl_xor(mx, off));
  for (int e = s0 + lane; e < s1; e += 64) {
    float v = __expf(ex[e] - mx);
    ex[e] = v;
    sm += v;
  }
  sm = wave_sum(sm);
  if (lane == 0) sums[n] = sm;
}

// writes h2 as fp16 (A-operand of the layer-0 input MFMA)
__global__ __launch_bounds__(256) void k_gat2_agg(
    const int* __restrict__ csr_src, const int* __restrict__ indptr,
    const float* __restrict__ ex, const float* __restrict__ sums,
    const float* __restrict__ hlin2, const float* __restrict__ b2,
    unsigned short* __restrict__ h2f16) {
  int w = threadIdx.x >> 6, lane = threadIdx.x & 63;
  int n = blockIdx.x * 4 + w;
  int s0 = indptr[n], s1 = indptr[n + 1];
  float inv = 1.f / (sums[n] + 1e-16f);
  float acc = 0.f;
  for (int e = s0; e < s1; ++e) {
    int s = csr_src[e];
    acc = fmaf(ex[e] * inv, hlin2[(size_t)s * HID_ + lane], acc);
  }
  h2f16[(size_t)n * HID_ + lane] = f2h(acc + b2[lane]);
}

// ---------------- MFMA GRU step (t-outer, fp16 states, LDS-only epilogues) ----
// fp16x2: C += A*(Bh+Bl); A single fp16, W split fp16 hi/lo
__device__ __forceinline__ void mfma2h(f4v& acc, h8v a, h8v bh, h8v bl) {
  acc = __builtin_amdgcn_mfma_f32_16x16x32_f16(a, bh, acc, 0, 0, 0);
  acc = __builtin_amdgcn_mfma_f32_16x16x32_f16(a, bl, acc, 0, 0, 0);
}

// LDS state pass: wave w owns one 16-col N-tile per gate (r: w, z: 8+w, n: 16+w)
__device__ __forceinline__ void mfma_pass(
    const unsigned short* A_,
    const unsigned short* __restrict__ Bh_, const unsigned short* __restrict__ Bl_,
    int w, int lane, f4v Cr[MT_], f4v Cz[MT_], f4v Cn[MT_]) {
  const int mrow = lane & 15, quad = lane >> 4;
#pragma unroll
  for (int ks = 0; ks < 4; ++ks) {
    h8v A[MT_];
    const int aoff = mrow * LDP_ + ks * 32 + quad * 8;
#pragma unroll
    for (int mt = 0; mt < MT_; ++mt) A[mt] = *(const h8v*)(A_ + aoff + mt * (16 * LDP_));
    {
      const int nt = w;
      const h8v bh = *(const h8v*)(Bh_ + ((size_t)(nt * 4 + ks) * 64 + lane) * 8);
      const h8v bl = *(const h8v*)(Bl_ + ((size_t)(nt * 4 + ks) * 64 + lane) * 8);
#pragma unroll
      for (int mt = 0; mt < MT_; ++mt) mfma2h(Cr[mt], A[mt], bh, bl);
    }
    {
      const int nt = 8 + w;
      const h8v bh = *(const h8v*)(Bh_ + ((size_t)(nt * 4 + ks) * 64 + lane) * 8);
      const h8v bl = *(const h8v*)(Bl_ + ((size_t)(nt * 4 + ks) * 64 + lane) * 8);
#pragma unroll
      for (int mt = 0; mt < MT_; ++mt) mfma2h(Cz[mt], A[mt], bh, bl);
    }
    {
      const int nt = 16 + w;
      const h8v bh = *(const h8v*)(Bh_ + ((size_t)(nt * 4 + ks) * 64 + lane) * 8);
      const h8v bl = *(const h8v*)(Bl_ + ((size_t)(nt * 4 + ks) * 64 + lane) * 8);
#pragma unroll
      for (int mt = 0; mt < MT_; ++mt) mfma2h(Cn[mt], A[mt], bh, bl);
    }
  }
}

// X pass (gi0): A from h2 slice, node-gathered (single-t slice -> L2-hot)
__device__ __forceinline__ void mfma_pass_x(
    const unsigned short* __restrict__ h2,
    const int esrc[MT_], const int edst[MT_],
    const unsigned short* __restrict__ Bh_, const unsigned short* __restrict__ Bl_,
    int w, int lane, f4v Cr[MT_], f4v Cz[MT_], f4v Cn[MT_]) {
  const int quad = lane >> 4;
#pragma unroll
  for (int ks = 0; ks < 4; ++ks) {
    h8v A[MT_];
    const int choff = (ks & 1) * 32 + quad * 8;
#pragma unroll
    for (int mt = 0; mt < MT_; ++mt) {
      const int node = (ks < 2) ? esrc[mt] : edst[mt];
      A[mt] = *(const h8v*)(h2 + (size_t)node * HID_ + choff);
    }
    {
      const int nt = w;
      const h8v bh = *(const h8v*)(Bh_ + ((size_t)(nt * 4 + ks) * 64 + lane) * 8);
      const h8v bl = *(const h8v*)(Bl_ + ((size_t)(nt * 4 + ks) * 64 + lane) * 8);
#pragma unroll
      for (int mt = 0; mt < MT_; ++mt) mfma2h(Cr[mt], A[mt], bh, bl);
    }
    {
      const int nt = 8 + w;
      const h8v bh = *(const h8v*)(Bh_ + ((size_t)(nt * 4 + ks) * 64 + lane) * 8);
      const h8v bl = *(const h8v*)(Bl_ + ((size_t)(nt * 4 + ks) * 64 + lane) * 8);
#pragma unroll
      for (int mt = 0; mt < MT_; ++mt) mfma2h(Cz[mt], A[mt], bh, bl);
    }
    {
      const int nt = 16 + w;
      const h8v bh = *(const h8v*)(Bh_ + ((size_t)(nt * 4 + ks) * 64 + lane) * 8);
      const h8v bl = *(const h8v*)(Bl_ + ((size_t)(nt * 4 + ks) * 64 + lane) * 8);
#pragma unroll
      for (int mt = 0; mt < MT_; ++mt) mfma2h(Cn[mt], A[mt], bh, bl);
    }
  }
}

// One GRU time-step for one edge segment; all resident blocks share t.
// fp16 states staged LDS<->global with pure 16B copies; epilogues write LDS
// only; single coalesced flush after the last barrier.
__global__ __launch_bounds__(512, 4) void k_gru_step(
    const unsigned short* __restrict__ h2, const int* __restrict__ ei,
    int seg_e0, int first, int last,
    const unsigned short* __restrict__ pWih0h, const unsigned short* __restrict__ pWih0l,
    const unsigned short* __restrict__ pWhh0h, const unsigned short* __restrict__ pWhh0l,
    const unsigned short* __restrict__ pWih1h, const unsigned short* __restrict__ pWih1l,
    const unsigned short* __restrict__ pWhh1h, const unsigned short* __restrict__ pWhh1l,
    const float* __restrict__ bih0, const float* __restrict__ bhh0,
    const float* __restrict__ bih1, const float* __restrict__ bhh1,
    const float* __restrict__ Wd1, const float* __restrict__ bd1,
    const float* __restrict__ Wd2, const float* __restrict__ bd2,
    unsigned short* __restrict__ h0g, unsigned short* __restrict__ h1g,
    float* __restrict__ out) {
  __shared__ unsigned short h0h[MB_ * LDP_];
  __shared__ unsigned short h1h[MB_ * LDP_];
  const int tid = threadIdx.x;
  const int lane = tid & 63, w = tid >> 6;
  const int col = lane & 15, quad = lane >> 4;
  const int mrow = lane & 15;
  const int le0 = blockIdx.x * MB_;
  const size_t ge0 = (size_t)seg_e0 + le0;

  // ---- stage fp16 states global -> LDS (pure 16B copies) ----
  if (!first) {
    for (int i = tid; i < MB_ * 16; i += 512) {
      int e = i >> 4, c = (i & 15) * 8;
      *(h8v*)&h0h[e * LDP_ + c] = *(const h8v*)(h0g + (size_t)(le0 + e) * GH_ + c);
      *(h8v*)&h1h[e * LDP_ + c] = *(const h8v*)(h1g + (size_t)(le0 + e) * GH_ + c);
    }
  }
  int esrc[MT_], edst[MT_];
#pragma unroll
  for (int mt = 0; mt < MT_; ++mt) {
    esrc[mt] = ei[ge0 + mt * 16 + mrow];
    edst[mt] = ei[E_ + ge0 + mt * 16 + mrow];
  }
  __syncthreads();

  const int cg = w * 16 + col;
  f4v Cr[MT_], Cz[MT_], Cin[MT_], Chn[MT_];

  // ---- layer 0 ----
#pragma unroll
  for (int mt = 0; mt < MT_; ++mt) {
    Cr[mt] = (f4v){0.f, 0.f, 0.f, 0.f};
    Cz[mt] = (f4v){0.f, 0.f, 0.f, 0.f};
    Cin[mt] = (f4v){0.f, 0.f, 0.f, 0.f};
    Chn[mt] = (f4v){0.f, 0.f, 0.f, 0.f};
  }
  mfma_pass_x(h2, esrc, edst, pWih0h, pWih0l, w, lane, Cr, Cz, Cin);
  if (!first) mfma_pass(h0h, pWhh0h, pWhh0l, w, lane, Cr, Cz, Chn);
  __syncthreads();   // gh0 reads of old h0h done (LDS drain only)
  {
    float biR = bih0[cg] + bhh0[cg];
    float biZ = bih0[128 + cg] + bhh0[128 + cg];
    float biNi = bih0[256 + cg], biNh = bhh0[256 + cg];
#pragma unroll
    for (int mt = 0; mt < MT_; ++mt)
#pragma unroll
      for (int reg = 0; reg < 4; ++reg) {
        int e = mt * 16 + quad * 4 + reg;
        float r = sigmoidf_(Cr[mt][reg] + biR);
        float z = sigmoidf_(Cz[mt][reg] + biZ);
        float n = tanhf_(Cin[mt][reg] + biNi + r * (Chn[mt][reg] + biNh));
        float hp = first ? 0.f : h2f(h0h[e * LDP_ + cg]);
        float hv = (1.f - z) * n + z * hp;
        h0h[e * LDP_ + cg] = f2h(hv);
      }
  }
  __syncthreads();   // new h0h visible

  // ---- layer 1 ----
#pragma unroll
  for (int mt = 0; mt < MT_; ++mt) {
    Cr[mt] = (f4v){0.f, 0.f, 0.f, 0.f};
    Cz[mt] = (f4v){0.f, 0.f, 0.f, 0.f};
    Cin[mt] = (f4v){0.f, 0.f, 0.f, 0.f};
    Chn[mt] = (f4v){0.f, 0.f, 0.f, 0.f};
  }
  mfma_pass(h0h, pWih1h, pWih1l, w, lane, Cr, Cz, Cin);
  if (!first) mfma_pass(h1h, pWhh1h, pWhh1l, w, lane, Cr, Cz, Chn);
  __syncthreads();   // old h1h reads done
  {
    float biR = bih1[cg] + bhh1[cg];
    float biZ = bih1[128 + cg] + bhh1[128 + cg];
    float biNi = bih1[256 + cg], biNh = bhh1[256 + cg];
#pragma unroll
    for (int mt = 0; mt < MT_; ++mt)
#pragma unroll
      for (int reg = 0; reg < 4; ++reg) {
        int e = mt * 16 + quad * 4 + reg;
        float r = sigmoidf_(Cr[mt][reg] + biR);
        float z = sigmoidf_(Cz[mt][reg] + biZ);
        float n = tanhf_(Cin[mt][reg] + biNi + r * (Chn[mt][reg] + biNh));
        float hp = first ? 0.f : h2f(h1h[e * LDP_ + cg]);
        float hv = (1.f - z) * n + z * hp;
        if (!last) {
          h1h[e * LDP_ + cg] = f2h(hv);
        } else {
          unsigned short hb = f2h(hv);
          h1h[e * LDP_ + cg] = hb;
          h0h[e * LDP_ + cg] = f2h(hv - h2f(hb));   // lo stash (h0h free)
        }
      }
  }
  __syncthreads();

  if (!last) {
    // ---- single coalesced flush LDS -> global ----
    for (int i = tid; i < MB_ * 16; i += 512) {
      int e = i >> 4, c = (i & 15) * 8;
      *(h8v*)(h0g + (size_t)(le0 + e) * GH_ + c) = *(const h8v*)&h0h[e * LDP_ + c];
      *(h8v*)(h1g + (size_t)(le0 + e) * GH_ + c) = *(const h8v*)&h1h[e * LDP_ + c];
    }
  } else {
    // ---- decoder: out = relu(h1 @ Wd1 + bd1) @ Wd2 + bd2 (vector LDS reads) ----
    for (int ee = 0; ee < MB_ / 8; ++ee) {
      int e = w * (MB_ / 8) + ee;
      float acc = 0.f;
#pragma unroll
      for (int kc = 0; kc < 16; ++kc) {
        h8v hv8 = *(const h8v*)&h1h[e * LDP_ + kc * 8];
        h8v lv8 = *(const h8v*)&h0h[e * LDP_ + kc * 8];
#pragma unroll
        for (int j = 0; j < 8; ++j) {
          float hvv = (float)hv8[j] + (float)lv8[j];
          acc = fmaf(hvv, Wd1[(kc * 8 + j) * 64 + lane], acc);
        }
      }
      float rv = fmaxf(acc + bd1[lane], 0.f);
      float contrib = wave_sum(rv * Wd2[lane]);
      if (lane == 0) out[ge0 + e] = contrib + bd2[0];
    }
  }
}

// ---------------- launch ----------------
extern "C" void kernel_launch(void* const* d_in, const int* in_sizes, int n_in,
                              void* d_out, int out_size, void* d_ws, size_t ws_size,
                              hipStream_t stream) {
  (void)in_sizes; (void)n_in; (void)out_size; (void)ws_size;
  const float* x_seq = (const float*)d_in[0];
  const int*   ei    = (const int*)d_in[1];
  const float* W1    = (const float*)d_in[2];
  const float* as1   = (const float*)d_in[3];
  const float* ad1   = (const float*)d_in[4];
  const float* b1    = (const float*)d_in[5];
  const float* W2    = (const float*)d_in[6];
  const float* as2   = (const float*)d_in[7];
  const float* ad2   = (const float*)d_in[8];
  const float* b2    = (const float*)d_in[9];
  const float* Wih0  = (const float*)d_in[10];
  const float* Whh0  = (const float*)d_in[11];
  const float* bih0  = (const float*)d_in[12];
  const float* bhh0  = (const float*)d_in[13];
  const float* Wih1  = (const float*)d_in[14];
  const float* Whh1  = (const float*)d_in[15];
  const float* bih1  = (const float*)d_in[16];
  const float* bhh1  = (const float*)d_in[17];
  const float* Wd1   = (const float*)d_in[18];
  const float* bd1   = (const float*)d_in[19];
  const float* Wd2   = (const float*)d_in[20];
  const float* bd2   = (const float*)d_in[21];
  float* out = (float*)d_out;

  char* p = (char*)d_ws;
  auto alloc = [&](size_t bytes) -> char* {
    char* r = p;
    p += (bytes + 255) & ~(size_t)255;
    return r;
  };
  // persistent:
  unsigned short* h2_all = (unsigned short*)alloc((size_t)T_ * N_ * HID_ * 2);  // 20.5 MB
  unsigned short* pWih0h = (unsigned short*)alloc(NPACK_ * 2);
  unsigned short* pWih0l = (unsigned short*)alloc(NPACK_ * 2);
  unsigned short* pWhh0h = (unsigned short*)alloc(NPACK_ * 2);
  unsigned short* pWhh0l = (unsigned short*)alloc(NPACK_ * 2);
  unsigned short* pWih1h = (unsigned short*)alloc(NPACK_ * 2);
  unsigned short* pWih1l = (unsigned short*)alloc(NPACK_ * 2);
  unsigned short* pWhh1h = (unsigned short*)alloc(NPACK_ * 2);
  unsigned short* pWhh1l = (unsigned short*)alloc(NPACK_ * 2);
  int* counts   = (int*)alloc((size_t)N_ * 4);
  int* indptr   = (int*)alloc((size_t)(N_ + 1) * 4);
  int* cursors  = (int*)alloc((size_t)N_ * 4);
  int* csr      = (int*)alloc((size_t)ETOT_ * 4);
  // REGION: GAT scratch (phase 1) aliased with GRU fp16 states (phase 2).
  char* region = p;
  float* hlin1  = (float*)(region);
  char* q = region + (((size_t)N_ * C1_ * 4 + 255) & ~(size_t)255);
  float* h1out  = (float*)q; q += ((size_t)N_ * C1_ * 4 + 255) & ~(size_t)255;
  float* hlin2  = (float*)q; q += ((size_t)N_ * HID_ * 4 + 255) & ~(size_t)255;
  float* als1   = (float*)q; q += ((size_t)N_ * 16 + 255) & ~(size_t)255;
  float* ald1   = (float*)q; q += ((size_t)N_ * 16 + 255) & ~(size_t)255;
  float* sums1  = (float*)q; q += ((size_t)N_ * 16 + 255) & ~(size_t)255;
  float* als2   = (float*)q; q += ((size_t)N_ * 4 + 255) & ~(size_t)255;
  float* ald2   = (float*)q; q += ((size_t)N_ * 4 + 255) & ~(size_t)255;
  float* sums2  = (float*)q; q += ((size_t)N_ * 4 + 255) & ~(size_t)255;
  float* ex1    = (float*)q; q += ((size_t)ETOT_ * 16 + 255) & ~(size_t)255;
  float* ex2    = (float*)q; q += ((size_t)ETOT_ * 4 + 255) & ~(size_t)255;
  // GRU view (same region): fp16 states 2 x 41 MB
  unsigned short* h0g = (unsigned short*)(region);
  unsigned short* h1g = (unsigned short*)(region + (((size_t)ESEG_ * GH_ * 2 + 255) & ~(size_t)255));

  (void)hipMemsetAsync(counts, 0, (size_t)N_ * 4, stream);

  k_hist<<<(ETOT_ + 255) / 256, 256, 0, stream>>>(ei, counts);
  k_scan<<<1, 1024, 0, stream>>>(counts, indptr);
  k_copy<<<(N_ + 255) / 256, 256, 0, stream>>>(indptr, cursors);
  k_scatter<<<(ETOT_ + 255) / 256, 256, 0, stream>>>(ei, cursors, csr);
  const int pb = (NPACK_ + 255) / 256;
  k_packW16<<<pb, 256, 0, stream>>>(Wih0, pWih0h, pWih0l);
  k_packW16<<<pb, 256, 0, stream>>>(Whh0, pWhh0h, pWhh0l);
  k_packW16<<<pb, 256, 0, stream>>>(Wih1, pWih1h, pWih1l);
  k_packW16<<<pb, 256, 0, stream>>>(Whh1, pWhh1h, pWhh1l);

  for (int t = 0; t < T_; ++t) {
    const float* xt = x_seq + (size_t)t * N_ * FIN_;
    unsigned short* h2t = h2_all + (size_t)t * N_ * HID_;
    k_gat1_lin<<<N_, 256, 0, stream>>>(xt, W1, as1, ad1, hlin1, als1, ald1);
    k_gat1_attn<<<N_ / 4, 256, 0, stream>>>(csr, indptr, als1, ald1, ex1, sums1);
    k_gat1_agg<<<N_, 256, 0, stream>>>(csr, indptr, ex1, sums1, hlin1, b1, h1out);
    k_gat2_lin<<<N_ / 4, 256, 0, stream>>>(h1out, W2, as2, ad2, hlin2, als2, ald2);
    k_gat2_attn<<<N_ / 4, 256, 0, stream>>>(csr, indptr, als2, ald2, ex2, sums2);
    k_gat2_agg<<<N_ / 4, 256, 0, stream>>>(csr, indptr, ex2, sums2, hlin2, b2, h2t);
  }

  for (int seg = 0; seg < SEG_; ++seg) {
    for (int t = 0; t < T_; ++t) {
      const unsigned short* h2t = h2_all + (size_t)t * N_ * HID_;
      k_gru_step<<<ESEG_ / MB_, 512, 0, stream>>>(
          h2t, ei, seg * ESEG_, (t == 0) ? 1 : 0, (t == T_ - 1) ? 1 : 0,
          pWih0h, pWih0l, pWhh0h, pWhh0l, pWih1h, pWih1l, pWhh1h, pWhh1l,
          bih0, bhh0, bih1, bhh1, Wd1, bd1, Wd2, bd2,
          h0g, h1g, out);
    }
  }
}